// Round 1
// baseline (3091.535 us; speedup 1.0000x reference)
//
#include <hip/hip_runtime.h>

// Problem constants
#define BATCH 4096
#define CCH   22
#define TT    1001   // usable time samples (input rows are 1002, last is subject id)
#define TROW  1002
#define KOUT  40
#define KSZ   25
#define WOUT  977    // 1001 - 25 + 1
#define POOL  100
#define NWIN  9
#define FEAT  360
#define NSUB  9
#define NOUT  4

#define CHUNK_W 300            // w-chunk per block (multiple of POOL)
#define NCHUNK  4              // 300,300,300,77
#define XROW    348            // LDS row stride: 315 (max lane base) + 29
#define NBLK    (BATCH * NCHUNK)

__device__ __forceinline__ float eluf(float v) {
    return v > 0.0f ? v : __expf(v) - 1.0f;
}

// Kernel A: conv + bias + ELU + pooled-window sums + per-block BN stat partials.
// grid (NCHUNK, BATCH), block 256. Wave w owns k = w*10..w*10+9; lane owns 5
// consecutive outputs (5 | 100 so a lane's outputs never straddle a pool window).
__global__ __launch_bounds__(256) void conv_elu_pool_kernel(
        const float* __restrict__ x, const float* __restrict__ cw,
        const float* __restrict__ cb, float* __restrict__ ps,
        float* __restrict__ sp) {
    __shared__ float xs[CCH * XROW];
    __shared__ float ps_s[KOUT * 3];
    __shared__ float st_s[KOUT * 2];

    const int chunk = blockIdx.x;
    const int b = blockIdx.y;
    const int chunk_base = chunk * CHUNK_W;
    const int chunk_len = min(CHUNK_W, WOUT - chunk_base);
    const size_t xb = (size_t)b * (CCH * TROW);

    // Stage x[b, :, chunk_base .. chunk_base+347] (zero-fill past t=1000)
    for (int c = 0; c < CCH; ++c) {
        for (int p = threadIdx.x; p < XROW; p += 256) {
            int g = chunk_base + p;
            xs[c * XROW + p] = (g < TT) ? x[xb + (size_t)c * TROW + g] : 0.0f;
        }
    }
    __syncthreads();

    const int wid = __builtin_amdgcn_readfirstlane(threadIdx.x >> 6);
    const int lane = threadIdx.x & 63;
    const int wb = lane * 5;   // lane's first output within chunk

    float acc[10][5];
#pragma unroll
    for (int kk = 0; kk < 10; ++kk)
#pragma unroll
        for (int i = 0; i < 5; ++i) acc[kk][i] = 0.0f;

#pragma unroll 1
    for (int c = 0; c < CCH; ++c) {
        float xr[29];
#pragma unroll
        for (int t = 0; t < 29; ++t) xr[t] = xs[c * XROW + wb + t];
#pragma unroll
        for (int kk = 0; kk < 10; ++kk) {
            const float* wk = cw + (wid * 10 + kk) * (CCH * KSZ) + c * KSZ;
            float wt[25];
#pragma unroll
            for (int j = 0; j < 25; ++j) wt[j] = wk[j];   // wave-uniform -> s_load
#pragma unroll
            for (int i = 0; i < 5; ++i)
#pragma unroll
                for (int j = 0; j < 25; ++j)
                    acc[kk][i] = fmaf(xr[i + j], wt[j], acc[kk][i]);
        }
    }

    // Epilogue: bias + ELU, wave-reduce stats, segment-reduce pool windows.
#pragma unroll
    for (int kk = 0; kk < 10; ++kk) {
        const int k = wid * 10 + kk;
        const float bias = cb[k];
        float s = 0.0f, q = 0.0f;
#pragma unroll
        for (int i = 0; i < 5; ++i) {
            if (wb + i < chunk_len) {
                float v = acc[kk][i] + bias;
                float e = eluf(v);
                s += e;
                q += e * e;
            }
        }
        // BN stats: reduce s,q over the whole wave
        float ss = s, qq = q;
#pragma unroll
        for (int m = 32; m; m >>= 1) {
            ss += __shfl_xor(ss, m, 64);
            qq += __shfl_xor(qq, m, 64);
        }
        if (lane == 0) { st_s[k * 2] = ss; st_s[k * 2 + 1] = qq; }

        // Pool: 20-lane groups (lanes 0..59 = 3 windows of 100 = 20 lanes x 5 w)
        float p = s;
        const int pos = lane % 20;
#pragma unroll
        for (int d = 16; d; d >>= 1) {
            float t = __shfl_down(p, d, 64);
            if (pos + d < 20) p += t;
        }
        if (chunk_len == CHUNK_W && pos == 0 && lane < 60) {
            int n_rel = wb / 100;              // 0..2
            ps_s[k * 3 + n_rel] = p;
        }
    }
    __syncthreads();

    const int t = threadIdx.x;
    if (t < KOUT * 2)
        sp[(size_t)(b * NCHUNK + chunk) * (KOUT * 2) + t] = st_s[t];
    if (chunk < 3 && t < KOUT * 3) {
        int k = t / 3, nr = t % 3;
        ps[(size_t)b * FEAT + k * NWIN + chunk * 3 + nr] = ps_s[k * 3 + nr];
    }
}

// Kernel B0: reduce per-block stat partials -> BN scale/shift per k. grid 40.
__global__ __launch_bounds__(256) void bn_stats_kernel(
        const float* __restrict__ sp, const float* __restrict__ gamma,
        const float* __restrict__ beta, float* __restrict__ scale,
        float* __restrict__ shift) {
    const int k = blockIdx.x;
    float s = 0.0f, q = 0.0f;
    for (int r = threadIdx.x; r < NBLK; r += 256) {
        s += sp[(size_t)r * (KOUT * 2) + k * 2];
        q += sp[(size_t)r * (KOUT * 2) + k * 2 + 1];
    }
#pragma unroll
    for (int m = 32; m; m >>= 1) {
        s += __shfl_xor(s, m, 64);
        q += __shfl_xor(q, m, 64);
    }
    __shared__ float rs[4], rq[4];
    const int wid = threadIdx.x >> 6, lane = threadIdx.x & 63;
    if (lane == 0) { rs[wid] = s; rq[wid] = q; }
    __syncthreads();
    if (threadIdx.x == 0) {
        s = rs[0] + rs[1] + rs[2] + rs[3];
        q = rq[0] + rq[1] + rq[2] + rq[3];
        const float N = (float)BATCH * (float)WOUT;
        float mean = s / N;
        float var = q / N - mean * mean;
        float sc = gamma[k] / sqrtf(var + 1e-5f);
        scale[k] = sc;
        shift[k] = beta[k] - mean * sc;
    }
}

// Kernel B1: subject decode + BN-affine fold + 360x4 matvec. grid BATCH, block 64.
__global__ __launch_bounds__(64) void fc_kernel(
        const float* __restrict__ x, const float* __restrict__ ps,
        const float* __restrict__ scale, const float* __restrict__ shift,
        const float* __restrict__ fcw, const float* __restrict__ fcb,
        float* __restrict__ out) {
    const int b = blockIdx.x;
    const int lane = threadIdx.x;
    const float idv = x[(size_t)b * (CCH * TROW) + (TT)];  // x[b, 0, -1]
    const int sid = (int)(idv * 1e-6f + 0.5f) - 1;
    const float* W = fcw + (size_t)sid * (FEAT * NOUT);
    float a0 = 0, a1 = 0, a2 = 0, a3 = 0;
    for (int f = lane; f < FEAT; f += 64) {
        int k = f / NWIN;
        float feat = fmaf(ps[(size_t)b * FEAT + f] * 0.01f, scale[k], shift[k]);
        a0 = fmaf(feat, W[f * 4 + 0], a0);
        a1 = fmaf(feat, W[f * 4 + 1], a1);
        a2 = fmaf(feat, W[f * 4 + 2], a2);
        a3 = fmaf(feat, W[f * 4 + 3], a3);
    }
#pragma unroll
    for (int m = 32; m; m >>= 1) {
        a0 += __shfl_xor(a0, m, 64);
        a1 += __shfl_xor(a1, m, 64);
        a2 += __shfl_xor(a2, m, 64);
        a3 += __shfl_xor(a3, m, 64);
    }
    if (lane == 0) {
        out[b * 4 + 0] = a0 + fcb[sid * 4 + 0];
        out[b * 4 + 1] = a1 + fcb[sid * 4 + 1];
        out[b * 4 + 2] = a2 + fcb[sid * 4 + 2];
        out[b * 4 + 3] = a3 + fcb[sid * 4 + 3];
    }
}

extern "C" void kernel_launch(void* const* d_in, const int* in_sizes, int n_in,
                              void* d_out, int out_size, void* d_ws, size_t ws_size,
                              hipStream_t stream) {
    const float* x     = (const float*)d_in[0];
    const float* cw    = (const float*)d_in[1];
    const float* cb    = (const float*)d_in[2];
    const float* gamma = (const float*)d_in[3];
    const float* beta  = (const float*)d_in[4];
    const float* fcw   = (const float*)d_in[5];
    const float* fcb   = (const float*)d_in[6];
    float* out = (float*)d_out;

    // workspace layout (all fp32):
    //   ps:  BATCH*FEAT                (pooled elu sums)        5.90 MB
    //   sp:  NBLK*KOUT*2               (per-block BN partials)  5.24 MB
    //   scale/shift: KOUT each                                  0.32 KB
    float* ps    = (float*)d_ws;
    float* sp    = ps + (size_t)BATCH * FEAT;
    float* scale = sp + (size_t)NBLK * (KOUT * 2);
    float* shift = scale + KOUT;

    conv_elu_pool_kernel<<<dim3(NCHUNK, BATCH), 256, 0, stream>>>(x, cw, cb, ps, sp);
    bn_stats_kernel<<<KOUT, 256, 0, stream>>>(sp, gamma, beta, scale, shift);
    fc_kernel<<<BATCH, 64, 0, stream>>>(x, ps, scale, shift, fcw, fcb, out);
}

// Round 2
// 910.691 us; speedup vs baseline: 3.3947x; 3.3947x over previous
//
#include <hip/hip_runtime.h>

// Problem constants
#define BATCH 4096
#define CCH   22
#define TT    1001   // usable time samples (row length is 1002; last elem = subject id)
#define TROW  1002
#define KOUT  40
#define KSZ   25
#define WOUT  977    // 1001 - 25 + 1
#define POOLW 100
#define NWIN  9      // 977 // 100
#define PUSED 900    // NWIN * POOLW (w >= 900 dropped by avgpool)
#define FEAT  360
#define NOUT  4

// Conv-MFMA tiling
#define WBLK  512              // w per block
#define NWB   2                // blocks along w  (2*512 = 1024 >= 977)
#define NBLK  (BATCH * NWB)
#define TSTG  544              // staged t rows (needs 536; padded to 34*16)
#define KP    48               // k_out padded to 3 MFMA n-tiles
#define CP    32               // channels padded to MFMA K
#define NLOC  6                // max pool windows per block

typedef __attribute__((ext_vector_type(8))) short short8;
typedef __attribute__((ext_vector_type(4))) float floatx4;

__device__ __forceinline__ unsigned short f2bf(float f) {
    unsigned u = __float_as_uint(f);
    u += 0x7fff + ((u >> 16) & 1);          // round-to-nearest-even
    return (unsigned short)(u >> 16);
}
__device__ __forceinline__ float eluf(float v) {
    return v > 0.0f ? v : __expf(v) - 1.0f;
}

// Pack conv weights into MFMA B-operand layout: wp[j][n=0..47][c=0..31] bf16,
// zero-padded past KOUT/CCH. 76.8 KB -> L2-resident for the conv kernel.
__global__ __launch_bounds__(256) void pack_w_kernel(const float* __restrict__ cw,
                                                     unsigned short* __restrict__ wp) {
    int i = blockIdx.x * 256 + threadIdx.x;      // over KSZ*KP*CP = 38400
    if (i >= KSZ * KP * CP) return;
    int c = i & (CP - 1);
    int n = (i >> 5) % KP;
    int j = i / (KP * CP);
    float v = (n < KOUT && c < CCH) ? cw[(n * CCH + c) * KSZ + j] : 0.0f;
    wp[i] = f2bf(v);
}

// Conv(bf16 MFMA) + bias + ELU + pool-window sums + per-block BN partials.
// grid (NWB, BATCH), block 256 (4 waves; wave wv owns w-range wv*128..+127).
__global__ __launch_bounds__(256) void conv_mfma_kernel(
        const float* __restrict__ x, const unsigned short* __restrict__ wp,
        const float* __restrict__ cb, float* __restrict__ ps,
        float* __restrict__ sp) {
    __shared__ unsigned short xt[TSTG * CP];     // 34816 B, [t][c] rows, swizzled
    __shared__ float ps_s[NLOC * KP];
    __shared__ float st_s[KOUT * 2];

    const int bx = blockIdx.x, b = blockIdx.y;
    const int w0 = bx * WBLK;
    const int tid = threadIdx.x;
    const int wv = __builtin_amdgcn_readfirstlane(tid >> 6);
    const int lane = tid & 63;
    const size_t xb = (size_t)b * (CCH * TROW);

    // zero LDS reduction buffers
    for (int i = tid; i < NLOC * KP + KOUT * 2; i += 256) {
        if (i < NLOC * KP) ps_s[i] = 0.0f;
        else st_s[i - NLOC * KP] = 0.0f;
    }

    // ---- stage x -> xt: bf16 rows of 32 channels, 16B-chunk XOR swizzle ----
    // chunk cc (8 channels) of row t stored at chunk slot cc ^ (t & 3).
    {
        const int tl16 = lane & 15, q = lane >> 4;
        for (int it = 0; it < 17; ++it) {
            int idx = wv * 17 + it;              // 0..67 = 34 t-groups x 2 c-halves
            int tg = idx >> 1, p = idx & 1;
            int t_loc = tg * 16 + tl16;          // 0..543
            int t_gl = w0 + t_loc;
            float v[4];
#pragma unroll
            for (int r = 0; r < 4; ++r) {
                int c = 16 * p + 4 * q + r;
                v[r] = (c < CCH && t_gl < TT) ? x[xb + (size_t)c * TROW + t_gl] : 0.0f;
            }
            unsigned d0 = (unsigned)f2bf(v[0]) | ((unsigned)f2bf(v[1]) << 16);
            unsigned d1 = (unsigned)f2bf(v[2]) | ((unsigned)f2bf(v[3]) << 16);
            int cc = 2 * p + (q >> 1);
            int off = t_loc * 64 + ((cc ^ (t_loc & 3)) << 4) + (q & 1) * 8;
            *(uint2*)((char*)xt + off) = make_uint2(d0, d1);
        }
    }
    __syncthreads();

    // ---- MFMA j-loop: acc[mt][nt] over 25 taps, K = 32 channels ----
    const int m16 = lane & 15, g = lane >> 4;
    floatx4 acc[8][3];
#pragma unroll
    for (int mt = 0; mt < 8; ++mt)
#pragma unroll
        for (int nt = 0; nt < 3; ++nt)
            acc[mt][nt] = (floatx4){0.f, 0.f, 0.f, 0.f};

    const int wvbase = wv * 128;
    const int t_lane = wvbase + m16;                       // + 16*mt + j
    const unsigned short* wpl = wp + (size_t)(m16 * CP + g * 8);

    short8 bfr[3];
#pragma unroll
    for (int nt = 0; nt < 3; ++nt)
        bfr[nt] = *(const short8*)(wpl + (size_t)(0 * KP + nt * 16) * CP);

#pragma unroll 1
    for (int j = 0; j < KSZ; ++j) {
        short8 bnx[3];
        if (j + 1 < KSZ) {
#pragma unroll
            for (int nt = 0; nt < 3; ++nt)
                bnx[nt] = *(const short8*)(wpl + (size_t)((j + 1) * KP + nt * 16) * CP);
        }
#pragma unroll
        for (int mt = 0; mt < 8; ++mt) {
            int t = t_lane + mt * 16 + j;
            int off = t * 64 + ((g ^ (t & 3)) << 4);
            short8 afr = *(const short8*)((const char*)xt + off);
#pragma unroll
            for (int nt = 0; nt < 3; ++nt)
                acc[mt][nt] = __builtin_amdgcn_mfma_f32_16x16x32_bf16(
                    afr, bfr[nt], acc[mt][nt], 0, 0, 0);
        }
#pragma unroll
        for (int nt = 0; nt < 3; ++nt) bfr[nt] = bnx[nt];
    }

    // ---- epilogue: bias + ELU, pool segmented-reduce, BN stat partials ----
    float bias[3];
#pragma unroll
    for (int nt = 0; nt < 3; ++nt) {
        int k = nt * 16 + m16;
        bias[nt] = (k < KOUT) ? cb[k] : 0.0f;
    }
    float sv[3] = {0.f, 0.f, 0.f}, qv[3] = {0.f, 0.f, 0.f};
    const int win0 = w0 / POOLW;

#pragma unroll
    for (int mt = 0; mt < 8; ++mt) {
        const int wbase = w0 + wvbase + mt * 16 + g * 4;   // lane's 4 w's: wbase..+3
#pragma unroll
        for (int nt = 0; nt < 3; ++nt) {
            const int k = nt * 16 + m16;
            const bool kok = (k < KOUT);
            float psum = 0.f;
#pragma unroll
            for (int r = 0; r < 4; ++r) {
                int w = wbase + r;
                float e = eluf(acc[mt][nt][r] + bias[nt]);
                if (kok && w < WOUT) { sv[nt] += e; qv[nt] += e * e; }
                if (kok && w < PUSED) psum += e;
            }
            // 4-aligned quad never straddles a 100-boundary -> one window/lane
            int win = (kok && wbase < PUSED) ? (wbase / POOLW) : -1;
            // segmented reduce over the 4 row-groups (g), segments are g-contiguous
            float o1 = __shfl_down(psum, 16); int w1 = __shfl_down(win, 16);
            if (lane < 48 && w1 == win) psum += o1;
            float o2 = __shfl_down(psum, 32); int w2 = __shfl_down(win, 32);
            if (lane < 32 && w2 == win) psum += o2;
            int wu = __shfl_up(win, 16);
            bool head = (g == 0) || (wu != win);
            if (head && win >= 0)
                atomicAdd(&ps_s[(win - win0) * KP + k], psum);
        }
    }
#pragma unroll
    for (int nt = 0; nt < 3; ++nt) {
        float s = sv[nt], q = qv[nt];
        s += __shfl_xor(s, 32); s += __shfl_xor(s, 16);
        q += __shfl_xor(q, 32); q += __shfl_xor(q, 16);
        int k = nt * 16 + m16;
        if (g == 0 && k < KOUT) {
            atomicAdd(&st_s[2 * k], s);
            atomicAdd(&st_s[2 * k + 1], q);
        }
    }
    __syncthreads();

    // per-block BN stat partials (plain store; reduced by bn_stats_kernel)
    if (tid < KOUT * 2)
        sp[(size_t)(b * NWB + bx) * (KOUT * 2) + tid] = st_s[tid];
    // pool-window partials -> global (windows straddle block boundaries)
    for (int i = tid; i < NLOC * KOUT; i += 256) {
        int wl = i / KOUT, k = i % KOUT;
        int win = win0 + wl;
        float v = ps_s[wl * KP + k];
        if (win < NWIN && v != 0.0f)
            atomicAdd(&ps[(size_t)b * FEAT + k * NWIN + win], v);
    }
}

// Reduce per-block stat partials -> BN scale/shift per k. grid KOUT.
__global__ __launch_bounds__(256) void bn_stats_kernel(
        const float* __restrict__ sp, const float* __restrict__ gamma,
        const float* __restrict__ beta, float* __restrict__ scale,
        float* __restrict__ shift) {
    const int k = blockIdx.x;
    float s = 0.0f, q = 0.0f;
    for (int r = threadIdx.x; r < NBLK; r += 256) {
        s += sp[(size_t)r * (KOUT * 2) + 2 * k];
        q += sp[(size_t)r * (KOUT * 2) + 2 * k + 1];
    }
#pragma unroll
    for (int m = 32; m; m >>= 1) {
        s += __shfl_xor(s, m, 64);
        q += __shfl_xor(q, m, 64);
    }
    __shared__ float rs[4], rq[4];
    const int wid = threadIdx.x >> 6, lane = threadIdx.x & 63;
    if (lane == 0) { rs[wid] = s; rq[wid] = q; }
    __syncthreads();
    if (threadIdx.x == 0) {
        s = rs[0] + rs[1] + rs[2] + rs[3];
        q = rq[0] + rq[1] + rq[2] + rq[3];
        const float N = (float)BATCH * (float)WOUT;
        float mean = s / N;
        float var = q / N - mean * mean;
        float sc = gamma[k] / sqrtf(var + 1e-5f);
        scale[k] = sc;
        shift[k] = beta[k] - mean * sc;
    }
}

// Subject decode + BN-affine fold + 360x4 matvec. grid BATCH, block 64.
__global__ __launch_bounds__(64) void fc_kernel(
        const float* __restrict__ x, const float* __restrict__ ps,
        const float* __restrict__ scale, const float* __restrict__ shift,
        const float* __restrict__ fcw, const float* __restrict__ fcb,
        float* __restrict__ out) {
    const int b = blockIdx.x;
    const int lane = threadIdx.x;
    const float idv = x[(size_t)b * (CCH * TROW) + TT];   // x[b, 0, -1]
    const int sid = (int)(idv * 1e-6f + 0.5f) - 1;
    const float* W = fcw + (size_t)sid * (FEAT * NOUT);
    float a0 = 0, a1 = 0, a2 = 0, a3 = 0;
    for (int f = lane; f < FEAT; f += 64) {
        int k = f / NWIN;
        float feat = fmaf(ps[(size_t)b * FEAT + f] * 0.01f, scale[k], shift[k]);
        a0 = fmaf(feat, W[f * 4 + 0], a0);
        a1 = fmaf(feat, W[f * 4 + 1], a1);
        a2 = fmaf(feat, W[f * 4 + 2], a2);
        a3 = fmaf(feat, W[f * 4 + 3], a3);
    }
#pragma unroll
    for (int m = 32; m; m >>= 1) {
        a0 += __shfl_xor(a0, m, 64);
        a1 += __shfl_xor(a1, m, 64);
        a2 += __shfl_xor(a2, m, 64);
        a3 += __shfl_xor(a3, m, 64);
    }
    if (lane == 0) {
        out[b * 4 + 0] = a0 + fcb[sid * 4 + 0];
        out[b * 4 + 1] = a1 + fcb[sid * 4 + 1];
        out[b * 4 + 2] = a2 + fcb[sid * 4 + 2];
        out[b * 4 + 3] = a3 + fcb[sid * 4 + 3];
    }
}

extern "C" void kernel_launch(void* const* d_in, const int* in_sizes, int n_in,
                              void* d_out, int out_size, void* d_ws, size_t ws_size,
                              hipStream_t stream) {
    const float* x     = (const float*)d_in[0];
    const float* cw    = (const float*)d_in[1];
    const float* cb    = (const float*)d_in[2];
    const float* gamma = (const float*)d_in[3];
    const float* beta  = (const float*)d_in[4];
    const float* fcw   = (const float*)d_in[5];
    const float* fcb   = (const float*)d_in[6];
    float* out = (float*)d_out;

    // workspace layout:
    //   ps: BATCH*FEAT f32 (pooled elu sums, atomically accumulated)  5.90 MB
    //   sp: NBLK*80  f32 (per-block BN partials)                      2.62 MB
    //   scale/shift: KOUT f32 each
    //   wp: KSZ*KP*CP bf16 (packed weights)                           76.8 KB
    float* ps    = (float*)d_ws;
    float* sp    = ps + (size_t)BATCH * FEAT;
    float* scale = sp + (size_t)NBLK * (KOUT * 2);
    float* shift = scale + KOUT;
    unsigned short* wpck = (unsigned short*)(shift + KOUT);

    hipMemsetAsync(ps, 0, (size_t)BATCH * FEAT * sizeof(float), stream);
    pack_w_kernel<<<(KSZ * KP * CP + 255) / 256, 256, 0, stream>>>(cw, wpck);
    conv_mfma_kernel<<<dim3(NWB, BATCH), 256, 0, stream>>>(x, wpck, cb, ps, sp);
    bn_stats_kernel<<<KOUT, 256, 0, stream>>>(sp, gamma, beta, scale, shift);
    fc_kernel<<<BATCH, 64, 0, stream>>>(x, ps, scale, shift, fcw, fcb, out);
}

// Round 3
// 828.378 us; speedup vs baseline: 3.7320x; 1.0994x over previous
//
#include <hip/hip_runtime.h>

// Problem constants
#define BATCH 4096
#define CCH   22
#define TT    1001   // usable time samples (row length 1002; last elem = subject id)
#define TROW  1002
#define KOUT  40
#define KSZ   25
#define WOUT  977    // 1001 - 25 + 1
#define POOLW 100
#define NWIN  9
#define FEAT  360
#define NOUT  4

// Conv-MFMA tiling: 4 blocks along w with exclusive ownership
//   block bx computes w in [w0, w0+256), owns [w0, oend) for stats+pool
//   w0  = {0, 252, 500, 752}, oend = {252, 500, 752, 977}  (all %4 == 0 except 977)
#define WBLK  256
#define NWB   4
#define NBLK  (BATCH * NWB)    // 16384
#define TSTG  280              // rows staged: 256 + 24
#define ROWB  80               // LDS row stride bytes (40 bf16; 5 coprime 8 -> conflict-free)
#define KP    48               // k_out padded to 3 MFMA n-tiles
#define CP    32               // channels padded to MFMA K
#define NLOC  4                // pool-window slots per block (incl. pseudo-windows >=9)

typedef __attribute__((ext_vector_type(8))) short short8;
typedef __attribute__((ext_vector_type(4))) float floatx4;

__device__ __forceinline__ unsigned short f2bf(float f) {
    unsigned u = __float_as_uint(f);
    u += 0x7fff + ((u >> 16) & 1);          // round-to-nearest-even
    return (unsigned short)(u >> 16);
}
__device__ __forceinline__ float eluf(float v) {
    return v > 0.0f ? v : __expf(v) - 1.0f;
}

// Pack conv weights into MFMA B-operand layout: wp[j][n=0..47][c=0..31] bf16.
__global__ __launch_bounds__(256) void pack_w_kernel(const float* __restrict__ cw,
                                                     unsigned short* __restrict__ wp) {
    int i = blockIdx.x * 256 + threadIdx.x;      // over KSZ*KP*CP = 38400
    if (i >= KSZ * KP * CP) return;
    int c = i & (CP - 1);
    int n = (i >> 5) % KP;
    int j = i / (KP * CP);
    float v = (n < KOUT && c < CCH) ? cw[(n * CCH + c) * KSZ + j] : 0.0f;
    wp[i] = f2bf(v);
}

// Conv(bf16 MFMA) + bias + ELU + owned pool-window sums + owned BN partials.
// grid (NWB, BATCH), block 256 = 4 waves; wave wv owns 64 w's (4 m-tiles).
__global__ __launch_bounds__(256, 4) void conv_mfma_kernel(
        const float* __restrict__ x, const unsigned short* __restrict__ wp,
        const float* __restrict__ cb, float* __restrict__ pparts,
        float* __restrict__ spS, float* __restrict__ spQ) {
    __shared__ unsigned short xt[TSTG * (ROWB / 2)];   // 22400 B
    __shared__ float ps_s[NLOC * KP];                  // 768 B
    __shared__ float st_q[KP];                         // 192 B

    const int bx = blockIdx.x, b = blockIdx.y;
    const int w0   = (bx == 0) ? 0   : (bx == 1 ? 252 : (bx == 2 ? 500 : 752));
    const int oend = (bx == 0) ? 252 : (bx == 1 ? 500 : (bx == 2 ? 752 : WOUT));
    const int tid = threadIdx.x;
    const int wv = __builtin_amdgcn_readfirstlane(tid >> 6);
    const int lane = tid & 63;
    const size_t xb = (size_t)b * (CCH * TROW);

    for (int i = tid; i < NLOC * KP + KP; i += 256) {
        if (i < NLOC * KP) ps_s[i] = 0.0f;
        else st_q[i - NLOC * KP] = 0.0f;
    }

    // ---- stage x -> xt[t][c] bf16, row stride 80 B (natural bank swizzle) ----
    {
        const int tl16 = lane & 15, q = lane >> 4;
#pragma unroll
        for (int it = 0; it < 9; ++it) {
            int idx = it * 4 + wv;               // 0..35: (t-group 0..17) x (c-half)
            int tg = idx >> 1, p = idx & 1;
            int t_loc = tg * 16 + tl16;
            if (t_loc < TSTG) {
                int t_gl = w0 + t_loc;
                float v[4];
#pragma unroll
                for (int r = 0; r < 4; ++r) {
                    int c = p * 16 + q * 4 + r;
                    v[r] = (c < CCH && t_gl < TT) ? x[xb + (size_t)c * TROW + t_gl] : 0.0f;
                }
                unsigned d0 = (unsigned)f2bf(v[0]) | ((unsigned)f2bf(v[1]) << 16);
                unsigned d1 = (unsigned)f2bf(v[2]) | ((unsigned)f2bf(v[3]) << 16);
                *(uint2*)((char*)xt + t_loc * ROWB + p * 32 + q * 8) = make_uint2(d0, d1);
            }
        }
    }
    __syncthreads();

    // ---- MFMA j-loop: K = 32 channels per tap, 25 taps, acc preloaded w/ bias ----
    const int m16 = lane & 15, g = lane >> 4;
    floatx4 acc[4][3];
#pragma unroll
    for (int nt = 0; nt < 3; ++nt) {
        int k = nt * 16 + m16;
        float bv = (k < KOUT) ? cb[k] : 0.0f;
#pragma unroll
        for (int mt = 0; mt < 4; ++mt) acc[mt][nt] = (floatx4){bv, bv, bv, bv};
    }

    const char* ap = (const char*)xt + (wv * 64 + m16) * ROWB + g * 16;
    const unsigned short* wpl = wp + m16 * CP + g * 8;

    short8 bfr[3];
#pragma unroll
    for (int nt = 0; nt < 3; ++nt)
        bfr[nt] = *(const short8*)(wpl + nt * 16 * CP);

#pragma unroll 1
    for (int j = 0; j < KSZ; ++j) {
        short8 bnx[3];
        if (j + 1 < KSZ) {
            const unsigned short* wn = wpl + (j + 1) * (KP * CP);
#pragma unroll
            for (int nt = 0; nt < 3; ++nt)
                bnx[nt] = *(const short8*)(wn + nt * 16 * CP);
        }
        short8 afr[4];
#pragma unroll
        for (int mt = 0; mt < 4; ++mt)
            afr[mt] = *(const short8*)(ap + mt * (16 * ROWB));
#pragma unroll
        for (int mt = 0; mt < 4; ++mt)
#pragma unroll
            for (int nt = 0; nt < 3; ++nt)
                acc[mt][nt] = __builtin_amdgcn_mfma_f32_16x16x32_bf16(
                    afr[mt], bfr[nt], acc[mt][nt], 0, 0, 0);
        ap += ROWB;
#pragma unroll
        for (int nt = 0; nt < 3; ++nt) bfr[nt] = bnx[nt];
    }

    // ---- epilogue: ELU, ownership mask, pool segmented-reduce, BN sumsq ----
    const int win0 = w0 / POOLW;
    float qv[3] = {0.f, 0.f, 0.f};
#pragma unroll
    for (int mt = 0; mt < 4; ++mt) {
        const int wbase = w0 + wv * 64 + mt * 16 + g * 4;  // 4-aligned quad
        const int win = wbase / POOLW;                     // quad never straddles
#pragma unroll
        for (int nt = 0; nt < 3; ++nt) {
            const int k = nt * 16 + m16;
            const bool kok = (k < KOUT);
            float psum = 0.f;
#pragma unroll
            for (int r = 0; r < 4; ++r) {
                int w = wbase + r;
                float e = eluf(acc[mt][nt][r]);
                e = (kok && w < oend) ? e : 0.0f;          // exclusive ownership
                psum += e;
                qv[nt] = fmaf(e, e, qv[nt]);
            }
            // segmented reduce over the 4 row-groups (g), segments g-contiguous
            float o1 = __shfl_down(psum, 16); int w1 = __shfl_down(win, 16);
            if (lane < 48 && w1 == win) psum += o1;
            float o2 = __shfl_down(psum, 32); int w2 = __shfl_down(win, 32);
            if (lane < 32 && w2 == win) psum += o2;
            int wu = __shfl_up(win, 16);
            if (g == 0 || wu != win)
                atomicAdd(&ps_s[(win - win0) * KP + k], psum);
        }
    }
#pragma unroll
    for (int nt = 0; nt < 3; ++nt) {
        float q = qv[nt];
        q += __shfl_xor(q, 16);
        q += __shfl_xor(q, 32);
        if (g == 0) atomicAdd(&st_q[nt * 16 + m16], q);
    }
    __syncthreads();

    const int blk = b * NWB + bx;
    if (tid < KOUT) {
        // stats sum = sum of all owned pool slots (incl. pseudo-windows 9,10)
        float s = ps_s[tid] + ps_s[KP + tid] + ps_s[2 * KP + tid] + ps_s[3 * KP + tid];
        spS[(size_t)tid * NBLK + blk] = s;               // transposed: coalesced reduce
        spQ[(size_t)tid * NBLK + blk] = st_q[tid];
    }
    if (tid < NLOC * KOUT) {
        int wl = tid / KOUT, k = tid - wl * KOUT;
        pparts[((size_t)blk * NLOC + wl) * KOUT + k] = ps_s[wl * KP + k];
    }
}

// Reduce per-block stat partials -> BN scale/shift per k. grid KOUT.
__global__ __launch_bounds__(256) void bn_stats_kernel(
        const float* __restrict__ spS, const float* __restrict__ spQ,
        const float* __restrict__ gamma, const float* __restrict__ beta,
        float* __restrict__ scale, float* __restrict__ shift) {
    const int k = blockIdx.x;
    float s = 0.0f, q = 0.0f;
    for (int r = threadIdx.x; r < NBLK; r += 256) {
        s += spS[(size_t)k * NBLK + r];
        q += spQ[(size_t)k * NBLK + r];
    }
#pragma unroll
    for (int m = 32; m; m >>= 1) {
        s += __shfl_xor(s, m, 64);
        q += __shfl_xor(q, m, 64);
    }
    __shared__ float rs[4], rq[4];
    const int wid = threadIdx.x >> 6, lane = threadIdx.x & 63;
    if (lane == 0) { rs[wid] = s; rq[wid] = q; }
    __syncthreads();
    if (threadIdx.x == 0) {
        s = rs[0] + rs[1] + rs[2] + rs[3];
        q = rq[0] + rq[1] + rq[2] + rq[3];
        const float N = (float)BATCH * (float)WOUT;
        float mean = s / N;
        float var = q / N - mean * mean;
        float sc = gamma[k] / sqrtf(var + 1e-5f);
        scale[k] = sc;
        shift[k] = beta[k] - mean * sc;
    }
}

// Subject decode + window-part merge + BN-affine fold + 360x4 matvec.
// Window->(block,slot) source tables packed as nibbles (win 0..8):
//   A: {0,1,2,5,6,8,9,10,13}  B: {15,15,4,15,15,7,15,12,15} (15 = none)
__global__ __launch_bounds__(64) void fc_kernel(
        const float* __restrict__ x, const float* __restrict__ pparts,
        const float* __restrict__ scale, const float* __restrict__ shift,
        const float* __restrict__ fcw, const float* __restrict__ fcb,
        float* __restrict__ out) {
    const int b = blockIdx.x;
    const int lane = threadIdx.x;
    const float idv = x[(size_t)b * (CCH * TROW) + TT];   // x[b, 0, -1]
    const int sid = (int)(idv * 1e-6f + 0.5f) - 1;
    const float* W = fcw + (size_t)sid * (FEAT * NOUT);
    const float* base = pparts + (size_t)b * (NWB * NLOC * KOUT);
    const unsigned long long TA = 0xDA9865210ULL;
    const unsigned long long TB = 0xFCF7FF4FFULL;
    float a0 = 0, a1 = 0, a2 = 0, a3 = 0;
    for (int f = lane; f < FEAT; f += 64) {
        int k = f / NWIN, win = f - k * NWIN;
        unsigned sa = (unsigned)(TA >> (4 * win)) & 15u;
        unsigned sb = (unsigned)(TB >> (4 * win)) & 15u;
        float p = base[sa * KOUT + k];
        if (sb != 15u) p += base[sb * KOUT + k];
        float feat = fmaf(p * 0.01f, scale[k], shift[k]);
        a0 = fmaf(feat, W[f * 4 + 0], a0);
        a1 = fmaf(feat, W[f * 4 + 1], a1);
        a2 = fmaf(feat, W[f * 4 + 2], a2);
        a3 = fmaf(feat, W[f * 4 + 3], a3);
    }
#pragma unroll
    for (int m = 32; m; m >>= 1) {
        a0 += __shfl_xor(a0, m, 64);
        a1 += __shfl_xor(a1, m, 64);
        a2 += __shfl_xor(a2, m, 64);
        a3 += __shfl_xor(a3, m, 64);
    }
    if (lane == 0) {
        out[b * 4 + 0] = a0 + fcb[sid * 4 + 0];
        out[b * 4 + 1] = a1 + fcb[sid * 4 + 1];
        out[b * 4 + 2] = a2 + fcb[sid * 4 + 2];
        out[b * 4 + 3] = a3 + fcb[sid * 4 + 3];
    }
}

extern "C" void kernel_launch(void* const* d_in, const int* in_sizes, int n_in,
                              void* d_out, int out_size, void* d_ws, size_t ws_size,
                              hipStream_t stream) {
    const float* x     = (const float*)d_in[0];
    const float* cw    = (const float*)d_in[1];
    const float* cb    = (const float*)d_in[2];
    const float* gamma = (const float*)d_in[3];
    const float* beta  = (const float*)d_in[4];
    const float* fcw   = (const float*)d_in[5];
    const float* fcb   = (const float*)d_in[6];
    float* out = (float*)d_out;

    // workspace layout (no memset needed: every slot is plain-stored):
    //   pparts: NBLK*NLOC*KOUT f32 (pool-window partials)   10.49 MB
    //   spS/spQ: KOUT*NBLK f32 each (BN partials, transposed) 5.24 MB
    //   scale/shift: KOUT f32 each; wp: 38400 bf16            76.8 KB
    float* pparts = (float*)d_ws;
    float* spS    = pparts + (size_t)NBLK * NLOC * KOUT;
    float* spQ    = spS + (size_t)KOUT * NBLK;
    float* scale  = spQ + (size_t)KOUT * NBLK;
    float* shift  = scale + KOUT;
    unsigned short* wpck = (unsigned short*)(shift + KOUT);

    pack_w_kernel<<<(KSZ * KP * CP + 255) / 256, 256, 0, stream>>>(cw, wpck);
    conv_mfma_kernel<<<dim3(NWB, BATCH), 256, 0, stream>>>(x, wpck, cb, pparts, spS, spQ);
    bn_stats_kernel<<<KOUT, 256, 0, stream>>>(spS, spQ, gamma, beta, scale, shift);
    fc_kernel<<<BATCH, 64, 0, stream>>>(x, pparts, scale, shift, fcw, fcb, out);
}